// Round 1
// baseline (577.128 us; speedup 1.0000x reference)
//
#include <hip/hip_runtime.h>
#include <math.h>

#define N_NODES 40000
#define E_EDGES 640000
#define IN_DIM 128
#define EDGE_DIM 64
#define HID 128
#define EB 10000   // edge blocks for k_edge (E/64)
#define NPART (EB * 4)

typedef unsigned int u32;
typedef unsigned short u16;
typedef __attribute__((ext_vector_type(4))) float f32x4;
typedef __attribute__((ext_vector_type(8))) short bf16x8;

__device__ __forceinline__ float bf_lo(u32 d) { return __uint_as_float(d << 16); }
__device__ __forceinline__ float bf_hi(u32 d) { return __uint_as_float(d & 0xffff0000u); }
__device__ __forceinline__ u16 f2bf(float f) {            // RNE
    u32 u = __float_as_uint(f);
    return (u16)((u + 0x7fffu + ((u >> 16) & 1u)) >> 16);
}
__device__ __forceinline__ u32 pack_bf(float lo, float hi) {
    return ((u32)f2bf(hi) << 16) | (u32)f2bf(lo);
}

// ---------------------------------------------------------------------------
// ws layout (8-B aligned block first):
//   sde  [E] uint2 : CSR payload (dst, bits(-exp(score)))
//   P1b [N*HID] u16, P2b [N*HID] u16, xb [N*IN] u16
//   Whtb [HID*EDGE_DIM] u16, WnAT [HID*IN] u16, WnBT [HID*IN] u16, fttb [IN*IN] u16
//   partials [NPART] f32, sumExp [1] f32
//   counts [N] u32, off [N+1] u32, cur [N] u32
// ---------------------------------------------------------------------------

__global__ __launch_bounds__(256) void k_init(const float* __restrict__ x,
                                              u16* __restrict__ xb,
                                              u32* __restrict__ counts) {
    int i = blockIdx.x * 256 + threadIdx.x;   // covers N*IN_DIM exactly
    xb[i] = f2bf(x[i]);
    if (i < N_NODES) counts[i] = 0;
}

// transpose+cast all weight matrices to bf16 [n][k] layouts (57344 elems)
__global__ __launch_bounds__(256) void k_trans(const float* __restrict__ Whw,
                                               const float* __restrict__ Wnw,
                                               const float* __restrict__ ftw,
                                               u16* __restrict__ Whtb,
                                               u16* __restrict__ WnAT,
                                               u16* __restrict__ WnBT,
                                               u16* __restrict__ fttb) {
    int i = blockIdx.x * 256 + threadIdx.x;
    if (i < 8192) {
        int h = i >> 6, k = i & 63;
        Whtb[i] = f2bf(Whw[k * HID + h]);
    } else if (i < 24576) {
        int j = i - 8192, h = j >> 7, k = j & 127;
        WnAT[j] = f2bf(Wnw[k * HID + h]);
    } else if (i < 40960) {
        int j = i - 24576, h = j >> 7, k = j & 127;
        WnBT[j] = f2bf(Wnw[(IN_DIM + k) * HID + h]);
    } else {
        int j = i - 40960, h = j >> 7, k = j & 127;
        fttb[j] = f2bf(ftw[k * IN_DIM + h]);
    }
}

// MFMA node projection: P1 = xb@WnA + (Whb+Wnb), P2 = xb@WnB  (bf16 out)
__global__ __launch_bounds__(256) void k_proj(const u16* __restrict__ xb,
                                              const u16* __restrict__ WnAT,
                                              const u16* __restrict__ WnBT,
                                              const float* __restrict__ Whb,
                                              const float* __restrict__ Wnb,
                                              u16* __restrict__ P1b,
                                              u16* __restrict__ P2b) {
    const int t = threadIdx.x, w = t >> 6, lane = t & 63;
    const int mrow = lane & 15, quad = lane >> 4;
    const int rowBase = blockIdx.x * 64 + w * 16;

    bf16x8 a[4];
    const u16* ar = xb + (size_t)(rowBase + mrow) * IN_DIM + quad * 8;
#pragma unroll
    for (int ks = 0; ks < 4; ++ks) a[ks] = *(const bf16x8*)(ar + ks * 32);

#pragma unroll
    for (int nt = 0; nt < 8; ++nt) {
        const u16* b1p = WnAT + (size_t)(nt * 16 + mrow) * IN_DIM + quad * 8;
        const u16* b2p = WnBT + (size_t)(nt * 16 + mrow) * IN_DIM + quad * 8;
        f32x4 c1 = {0.f, 0.f, 0.f, 0.f}, c2 = {0.f, 0.f, 0.f, 0.f};
#pragma unroll
        for (int ks = 0; ks < 4; ++ks) {
            c1 = __builtin_amdgcn_mfma_f32_16x16x32_bf16(a[ks], *(const bf16x8*)(b1p + ks * 32), c1, 0, 0, 0);
            c2 = __builtin_amdgcn_mfma_f32_16x16x32_bf16(a[ks], *(const bf16x8*)(b2p + ks * 32), c2, 0, 0, 0);
        }
        const int col = nt * 16 + mrow;
        const float bias = Whb[col] + Wnb[col];
#pragma unroll
        for (int r = 0; r < 4; ++r) {
            int row = rowBase + quad * 4 + r;
            P1b[(size_t)row * HID + col] = f2bf(c1[r] + bias);
            P2b[(size_t)row * HID + col] = f2bf(c2[r]);
        }
    }
}

__global__ __launch_bounds__(256) void k_hist(const int* __restrict__ eidx,
                                              u32* __restrict__ counts) {
    int e = blockIdx.x * 256 + threadIdx.x;   // E exactly
    atomicAdd(&counts[eidx[e]], 1u);
}

__global__ __launch_bounds__(1024) void k_scan(const u32* __restrict__ counts,
                                               u32* __restrict__ off,
                                               u32* __restrict__ cur) {
    __shared__ u32 sums[1024];
    const int t = threadIdx.x;
    const int CH = 40;
    u32 local[CH];
    u32 s = 0;
    const int base = t * CH;
#pragma unroll
    for (int i = 0; i < CH; ++i) {
        int idx = base + i;
        u32 c = (idx < N_NODES) ? counts[idx] : 0u;
        local[i] = s;
        s += c;
    }
    sums[t] = s;
    __syncthreads();
    for (int o = 1; o < 1024; o <<= 1) {
        u32 v = (t >= o) ? sums[t - o] : 0u;
        __syncthreads();
        sums[t] += v;
        __syncthreads();
    }
    const u32 pre = sums[t] - s;
#pragma unroll
    for (int i = 0; i < CH; ++i) {
        int idx = base + i;
        if (idx < N_NODES) {
            u32 v = pre + local[i];
            off[idx] = v;
            cur[idx] = v;
        }
    }
    if (t == 1023) off[N_NODES] = sums[1023];
}

// Wave-autonomous MFMA edge kernel + fused CSR fill. No LDS, no barriers.
// Each wave owns 16 edges. Node terms P1[src]/P2[dst] are gathered DIRECTLY
// in A-fragment layout and added through the matrix unit with a one-hot
// identity B fragment: D[row][nt*16+col] += P[row-edge][nt*16+col].
// For output col c=nt*16+mrow the hot k sits in window ks=nt>>1 at local
// offset L=mrow+16*(nt&1) -> hot lane quad=(mrow>>3)+2*(nt&1), elem j=mrow&7.
__global__ __launch_bounds__(256) void k_edge(const int* __restrict__ eidx,
                                              const float* __restrict__ ea,
                                              const u16* __restrict__ Whtb,
                                              const u16* __restrict__ P1b,
                                              const u16* __restrict__ P2b,
                                              const float* __restrict__ we,
                                              u32* __restrict__ cur,
                                              uint2* __restrict__ sde,
                                              float* __restrict__ partials) {
    const int t = threadIdx.x, w = t >> 6, lane = t & 63;
    const int e0 = blockIdx.x * 64 + w * 16;
    const int mrow = lane & 15, quad = lane >> 4;

    // --- issue ALL global loads up-front: lane's edge is mrow (A-row) ---
    const int srcm = eidx[e0 + mrow];
    const int dstm = eidx[E_EDGES + e0 + mrow];
    const u16* p1 = P1b + (size_t)srcm * HID + quad * 8;
    const u16* p2 = P2b + (size_t)dstm * HID + quad * 8;
    bf16x8 aP1[4], aP2[4];
#pragma unroll
    for (int ks = 0; ks < 4; ++ks) {
        aP1[ks] = *(const bf16x8*)(p1 + ks * 32);
        aP2[ks] = *(const bf16x8*)(p2 + ks * 32);
    }

    const float* arow = ea + (size_t)(e0 + mrow) * EDGE_DIM + quad * 8;
    float4 f0 = *(const float4*)(arow);
    float4 f1 = *(const float4*)(arow + 4);
    float4 f2 = *(const float4*)(arow + 32);
    float4 f3 = *(const float4*)(arow + 36);

    // --- one-hot identity B fragments (even nt / odd nt) ---
    bf16x8 bIe, bIo;
    {
        const int hotj = mrow & 7;
        const bool ce = (quad == (mrow >> 3));
        const bool co = (quad == 2 + (mrow >> 3));
#pragma unroll
        for (int j = 0; j < 8; ++j) {
            bIe[j] = (short)((ce && j == hotj) ? 0x3F80 : 0);
            bIo[j] = (short)((co && j == hotj) ? 0x3F80 : 0);
        }
    }

    // --- A fragments from ea (f32 -> bf16 in-register) ---
    bf16x8 a0, a1;
    a0[0] = (short)f2bf(f0.x); a0[1] = (short)f2bf(f0.y);
    a0[2] = (short)f2bf(f0.z); a0[3] = (short)f2bf(f0.w);
    a0[4] = (short)f2bf(f1.x); a0[5] = (short)f2bf(f1.y);
    a0[6] = (short)f2bf(f1.z); a0[7] = (short)f2bf(f1.w);
    a1[0] = (short)f2bf(f2.x); a1[1] = (short)f2bf(f2.y);
    a1[2] = (short)f2bf(f2.z); a1[3] = (short)f2bf(f2.w);
    a1[4] = (short)f2bf(f3.x); a1[5] = (short)f2bf(f3.y);
    a1[6] = (short)f2bf(f3.z); a1[7] = (short)f2bf(f3.w);

    // --- MFMA over 8 n-tiles; node term fused via identity-B MFMAs ---
    float wsum[4] = {0.f, 0.f, 0.f, 0.f};
    const u16* bbase = Whtb + (size_t)mrow * EDGE_DIM + quad * 8;
#pragma unroll
    for (int nt = 0; nt < 8; ++nt) {
        const u16* bp = bbase + nt * 16 * EDGE_DIM;
        bf16x8 b0 = *(const bf16x8*)(bp);
        bf16x8 b1 = *(const bf16x8*)(bp + 32);
        f32x4 c = {0.f, 0.f, 0.f, 0.f};
        c = __builtin_amdgcn_mfma_f32_16x16x32_bf16(a0, b0, c, 0, 0, 0);
        c = __builtin_amdgcn_mfma_f32_16x16x32_bf16(a1, b1, c, 0, 0, 0);
        const bf16x8 bI = (nt & 1) ? bIo : bIe;
        c = __builtin_amdgcn_mfma_f32_16x16x32_bf16(aP1[nt >> 1], bI, c, 0, 0, 0);
        c = __builtin_amdgcn_mfma_f32_16x16x32_bf16(aP2[nt >> 1], bI, c, 0, 0, 0);
        float wv = we[nt * 16 + mrow];
#pragma unroll
        for (int r = 0; r < 4; ++r)
            wsum[r] += fmaxf(c[r], 0.f) * wv;
    }

    // --- reduce across the 16 lanes of each quad group ---
#pragma unroll
    for (int off = 1; off < 16; off <<= 1) {
#pragma unroll
        for (int r = 0; r < 4; ++r) wsum[r] += __shfl_xor(wsum[r], off, 16);
    }
    float ex[4]; float s4 = 0.f;
#pragma unroll
    for (int r = 0; r < 4; ++r) { ex[r] = __expf(wsum[r]); s4 += ex[r]; }

    // --- fetch (src,dst) of this quad's 4 edges via shuffle (already in regs) ---
    u32 sArr[4], dArr[4];
#pragma unroll
    for (int r = 0; r < 4; ++r) {
        sArr[r] = (u32)__shfl(srcm, quad * 4 + r, 16);
        dArr[r] = (u32)__shfl(dstm, quad * 4 + r, 16);
    }

    // --- fused CSR fill: store (dst, -exp) unnormalized ---
    if (mrow == 0) {
#pragma unroll
        for (int r = 0; r < 4; ++r) {
            u32 pos = atomicAdd(&cur[sArr[r]], 1u);
            sde[pos] = make_uint2(dArr[r], __float_as_uint(-ex[r]));
        }
    }

    // --- per-wave partial (no atomics, no barrier) ---
    s4 += __shfl_xor(s4, 16, 64);
    s4 += __shfl_xor(s4, 32, 64);
    if (lane == 0) partials[blockIdx.x * 4 + w] = s4;
}

__global__ __launch_bounds__(256) void k_sum(const float* __restrict__ partials,
                                             float* __restrict__ sumExp) {
    float s = 0.f;
    for (int i = threadIdx.x; i < NPART; i += 256) s += partials[i];
#pragma unroll
    for (int off = 1; off < 64; off <<= 1) s += __shfl_xor(s, off, 64);
    __shared__ float ws4[4];
    if ((threadIdx.x & 63) == 0) ws4[threadIdx.x >> 6] = s;
    __syncthreads();
    if (threadIdx.x == 0) sumExp[0] = ws4[0] + ws4[1] + ws4[2] + ws4[3];
}

// one wave per node: out[n][:] = invS * sum_{edges of n} (-exp_e) * xb[dst][:]
__global__ __launch_bounds__(256) void k_accum(const u32* __restrict__ off,
                                               const uint2* __restrict__ sde,
                                               const float* __restrict__ sumExp,
                                               const u16* __restrict__ xb,
                                               float* __restrict__ out) {
    const float invS = 1.0f / sumExp[0];
    const int lane = threadIdx.x & 63;
    const int n = blockIdx.x * 4 + (threadIdx.x >> 6);
    const u32 o0 = off[n], o1 = off[n + 1];

    float acc0 = 0.f, acc1 = 0.f;
    for (u32 base = o0; base < o1; base += 64) {
        u32 j = base + (u32)lane;
        uint2 dv = make_uint2(0u, 0u);
        if (j < o1) dv = sde[j];
        int cnt = (int)min(64u, o1 - base);
        int jj = 0;
        for (; jj + 4 <= cnt; jj += 4) {
            u32 d0 = __shfl(dv.x, jj, 64),     d1 = __shfl(dv.x, jj + 1, 64);
            u32 d2 = __shfl(dv.x, jj + 2, 64), d3 = __shfl(dv.x, jj + 3, 64);
            float a0 = __uint_as_float(__shfl(dv.y, jj, 64));
            float a1 = __uint_as_float(__shfl(dv.y, jj + 1, 64));
            float a2 = __uint_as_float(__shfl(dv.y, jj + 2, 64));
            float a3 = __uint_as_float(__shfl(dv.y, jj + 3, 64));
            u32 q0 = ((const u32*)(xb + (size_t)d0 * IN_DIM))[lane];
            u32 q1 = ((const u32*)(xb + (size_t)d1 * IN_DIM))[lane];
            u32 q2 = ((const u32*)(xb + (size_t)d2 * IN_DIM))[lane];
            u32 q3 = ((const u32*)(xb + (size_t)d3 * IN_DIM))[lane];
            acc0 = fmaf(a0, bf_lo(q0), acc0); acc1 = fmaf(a0, bf_hi(q0), acc1);
            acc0 = fmaf(a1, bf_lo(q1), acc0); acc1 = fmaf(a1, bf_hi(q1), acc1);
            acc0 = fmaf(a2, bf_lo(q2), acc0); acc1 = fmaf(a2, bf_hi(q2), acc1);
            acc0 = fmaf(a3, bf_lo(q3), acc0); acc1 = fmaf(a3, bf_hi(q3), acc1);
        }
        for (; jj < cnt; ++jj) {
            u32 dst = __shfl(dv.x, jj, 64);
            float a = __uint_as_float(__shfl(dv.y, jj, 64));
            u32 q = ((const u32*)(xb + (size_t)dst * IN_DIM))[lane];
            acc0 = fmaf(a, bf_lo(q), acc0);
            acc1 = fmaf(a, bf_hi(q), acc1);
        }
    }
    float* op = out + (size_t)n * IN_DIM + 2 * lane;
    op[0] = acc0 * invS;
    op[1] = acc1 * invS;
}

// MFMA finisher: out = y + y@ft + ftb, y = x + local(out). In-place per row-block.
__global__ __launch_bounds__(256) void k_final(const float* __restrict__ x,
                                               const u16* __restrict__ fttb,
                                               const float* __restrict__ ftb,
                                               float* __restrict__ out) {
    __shared__ u32 ybp[64][68];   // packed bf16 y
    const int t = threadIdx.x;
    const int rb = blockIdx.x * 64;

    {   // stage y = x + local as packed bf16
        const int rr = t >> 2, seg = t & 3;
        const float4* xp = (const float4*)(x + (size_t)(rb + rr) * IN_DIM + seg * 32);
        const float4* lp = (const float4*)(out + (size_t)(rb + rr) * IN_DIM + seg * 32);
#pragma unroll
        for (int i = 0; i < 4; ++i) {
            float4 xa = xp[2 * i], xc = xp[2 * i + 1];
            float4 la = lp[2 * i], lc = lp[2 * i + 1];
            uint4 o;
            o.x = pack_bf(xa.x + la.x, xa.y + la.y);
            o.y = pack_bf(xa.z + la.z, xa.w + la.w);
            o.z = pack_bf(xc.x + lc.x, xc.y + lc.y);
            o.w = pack_bf(xc.z + lc.z, xc.w + lc.w);
            *(uint4*)&ybp[rr][seg * 16 + i * 4] = o;
        }
    }
    __syncthreads();

    const int w = t >> 6, lane = t & 63;
    const int mrow = lane & 15, quad = lane >> 4;
    const int rowBase = rb + w * 16;

    bf16x8 a[4];
#pragma unroll
    for (int ks = 0; ks < 4; ++ks)
        a[ks] = *(const bf16x8*)&ybp[w * 16 + mrow][ks * 16 + quad * 4];

#pragma unroll
    for (int nt = 0; nt < 8; ++nt) {
        const u16* bp = fttb + (size_t)(nt * 16 + mrow) * IN_DIM + quad * 8;
        f32x4 c = {0.f, 0.f, 0.f, 0.f};
#pragma unroll
        for (int ks = 0; ks < 4; ++ks)
            c = __builtin_amdgcn_mfma_f32_16x16x32_bf16(a[ks], *(const bf16x8*)(bp + ks * 32), c, 0, 0, 0);
        const int col = nt * 16 + mrow;
        const float fb = ftb[col];
#pragma unroll
        for (int r = 0; r < 4; ++r) {
            int row = rowBase + quad * 4 + r;
            size_t idx = (size_t)row * IN_DIM + col;
            float y = x[idx] + out[idx];      // exact fp32 y term
            out[idx] = y + c[r] + fb;
        }
    }
}

extern "C" void kernel_launch(void* const* d_in, const int* in_sizes, int n_in,
                              void* d_out, int out_size, void* d_ws, size_t ws_size,
                              hipStream_t stream) {
    const float* x    = (const float*)d_in[0];
    const int*   eidx = (const int*)d_in[1];
    const float* ea   = (const float*)d_in[2];
    const float* Whw  = (const float*)d_in[3];
    const float* Whb  = (const float*)d_in[4];
    const float* Wnw  = (const float*)d_in[5];
    const float* Wnb  = (const float*)d_in[6];
    const float* we   = (const float*)d_in[7];
    const float* ftw  = (const float*)d_in[8];
    const float* ftb  = (const float*)d_in[9];
    float* out = (float*)d_out;

    uint2* sde      = (uint2*)d_ws;                       // 8-B aligned first
    u16*   P1b      = (u16*)(sde + (size_t)E_EDGES);
    u16*   P2b      = P1b + (size_t)N_NODES * HID;
    u16*   xb       = P2b + (size_t)N_NODES * HID;
    u16*   Whtb     = xb + (size_t)N_NODES * IN_DIM;
    u16*   WnAT     = Whtb + (size_t)EDGE_DIM * HID;
    u16*   WnBT     = WnAT + (size_t)HID * IN_DIM;
    u16*   fttb     = WnBT + (size_t)HID * IN_DIM;
    float* partials = (float*)(fttb + (size_t)IN_DIM * IN_DIM);
    float* sumExp   = partials + NPART;
    u32*   counts   = (u32*)(sumExp + 1);
    u32*   off      = counts + N_NODES;
    u32*   cur      = off + N_NODES + 1;

    k_init <<<(N_NODES * IN_DIM) / 256, 256, 0, stream>>>(x, xb, counts);
    k_trans<<<224, 256, 0, stream>>>(Whw, Wnw, ftw, Whtb, WnAT, WnBT, fttb);
    k_proj <<<N_NODES / 64, 256, 0, stream>>>(xb, WnAT, WnBT, Whb, Wnb, P1b, P2b);
    k_hist <<<E_EDGES / 256, 256, 0, stream>>>(eidx, counts);
    k_scan <<<1, 1024, 0, stream>>>(counts, off, cur);
    k_edge <<<EB, 256, 0, stream>>>(eidx, ea, Whtb, P1b, P2b, we, cur, sde, partials);
    k_sum  <<<1, 256, 0, stream>>>(partials, sumExp);
    k_accum<<<N_NODES / 4, 256, 0, stream>>>(off, sde, sumExp, xb, out);
    k_final<<<N_NODES / 64, 256, 0, stream>>>(x, fttb, ftb, out);
}